// Round 8
// baseline (195.724 us; speedup 1.0000x reference)
//
#include <hip/hip_runtime.h>
#include <hip/hip_bf16.h>

typedef short bf16x8 __attribute__((ext_vector_type(8)));
typedef float f32x4 __attribute__((ext_vector_type(4)));

static constexpr int M_DIM = 16384;
static constexpr int N_DIM = 4096;
static constexpr int K_DIM = 1024;

static constexpr int CVT_BLOCKS = (M_DIM * K_DIM / 8) / 256;   // 8192
static constexpr int WT_BLOCKS  = 128;                         // one per j

__device__ __forceinline__ unsigned short f2bf(float f) {
  union { float f; unsigned u; } v; v.f = f;
  unsigned r = v.u + 0x7FFFu + ((v.u >> 16) & 1u);
  return (unsigned short)(r >> 16);
}

// Fused prep: blocks [0, CVT_BLOCKS) convert x f32->bf16 (8 elems/thread);
// blocks [CVT_BLOCKS, +128) build w^T for one j each (32 columns), staging the
// ENTIRE b (16 KB) + a*s column once -> no scattered global re-reads.
__global__ __launch_bounds__(256) void prep_kernel(
    const float* __restrict__ x, const float* __restrict__ a,
    const float* __restrict__ b, const float* __restrict__ s,
    unsigned short* __restrict__ xb, unsigned short* __restrict__ wT) {
  const int tid = threadIdx.x;

  if (blockIdx.x < CVT_BLOCKS) {
    const int i = (blockIdx.x * 256 + tid) * 2;     // float4 pair
    float4 v0 = reinterpret_cast<const float4*>(x)[i];
    float4 v1 = reinterpret_cast<const float4*>(x)[i + 1];
    ushort4 o0, o1;
    o0.x = f2bf(v0.x); o0.y = f2bf(v0.y); o0.z = f2bf(v0.z); o0.w = f2bf(v0.w);
    o1.x = f2bf(v1.x); o1.y = f2bf(v1.y); o1.z = f2bf(v1.z); o1.w = f2bf(v1.w);
    reinterpret_cast<ushort4*>(xb)[i] = o0;
    reinterpret_cast<ushort4*>(xb)[i + 1] = o1;
    return;
  }

  __shared__ float as_eff[8][64];     // a[r][i][j]*s[i][j] for this j
  __shared__ float bsh[8][16][32];    // full b, 16 KB
  const int j = blockIdx.x - CVT_BLOCKS;          // 0..127

#pragma unroll
  for (int t = tid; t < 4096; t += 256)
    ((float*)bsh)[t] = b[t];                      // coalesced, layout-identical
#pragma unroll
  for (int t = tid; t < 512; t += 256) {
    const int r = t >> 6, i = t & 63;
    as_eff[r][i] = a[(r * 64 + i) * 128 + j] * s[i * 128 + j];
  }
  __syncthreads();

  // thread: i = tid>>2, kk0 = (tid&3)*4 ; covers k = tid*4..+3 for all 32 l
  const int i = tid >> 2;
  const int kk0 = (tid & 3) * 4;
  float av[8];
#pragma unroll
  for (int r = 0; r < 8; ++r) av[r] = as_eff[r][i];

#pragma unroll 4
  for (int l = 0; l < 32; ++l) {
    float o[4] = {0.f, 0.f, 0.f, 0.f};
#pragma unroll
    for (int r = 0; r < 8; ++r)
#pragma unroll
      for (int q = 0; q < 4; ++q)
        o[q] += av[r] * bsh[r][kk0 + q][l];
    ushort4 w4;
    w4.x = f2bf(o[0]); w4.y = f2bf(o[1]); w4.z = f2bf(o[2]); w4.w = f2bf(o[3]);
    *reinterpret_cast<ushort4*>(&wT[(size_t)(j * 32 + l) * K_DIM + tid * 4]) = w4;
  }
}

// ------ 256x256 GEMM, ONE barrier/K-tile: 3-deep B ring kills mid-barrier ------
// C(M,N) = A(M,K) * BT(N,K)^T + bias ; A,BT bf16, C f32.
// 512 threads = 8 waves (2 M x 4 N). Per wave: 128x64 out = 8x4 frags 16x16.
// LDS: Al[2] (64 KB) + Bl[3] (96 KB) = 160 KiB exactly -> 1 block/CU.
// Tile t: reads Al[t&1], Bl[t%3]; stages A_{t+1}->Al[~t&1] and B_{t+2}->
// Bl[(t+2)%3] AT ENTRY — both targets' readers drained before the previous
// publish barrier (each wave hits lgkmcnt(0) before its last quadrant), so no
// mid-tile barrier is needed. Publish: vmcnt(4) leaves B_{t+2} in flight (T4).
// Steady queue at publish: [B_{t+1}(4), A_{t+1}(4), B_{t+2}(4)] -> vmcnt(4).

#define PH_BARRIER __builtin_amdgcn_s_barrier()
#define SCHED0     __builtin_amdgcn_sched_barrier(0)
#define WAITV(N)   do { asm volatile("s_waitcnt vmcnt(" #N ")" ::: "memory"); SCHED0; } while (0)
#define WAITL(N)   do { asm volatile("s_waitcnt lgkmcnt(" #N ")" ::: "memory"); SCHED0; } while (0)

__device__ __forceinline__ void quad_mfma(f32x4 (&acc)[8][4], const bf16x8 (&aH)[4][2],
                                          const bf16x8 (&bH)[2][2], int mbase, int nbase) {
  __builtin_amdgcn_s_setprio(1);
#pragma unroll
  for (int ks = 0; ks < 2; ++ks)
#pragma unroll
    for (int mi = 0; mi < 4; ++mi)
#pragma unroll
      for (int ni = 0; ni < 2; ++ni)
        acc[mbase + mi][nbase + ni] = __builtin_amdgcn_mfma_f32_16x16x32_bf16(
            aH[mi][ks], bH[ni][ks], acc[mbase + mi][nbase + ni], 0, 0, 0);
  __builtin_amdgcn_s_setprio(0);
}

__global__ __launch_bounds__(512, 2) void gemm8_kernel(
    const unsigned short* __restrict__ A, const unsigned short* __restrict__ BT,
    const float* __restrict__ bias, float* __restrict__ C) {
  __shared__ __align__(16) unsigned short Al[2][16384];
  __shared__ __align__(16) unsigned short Bl[3][16384];

  const int tid  = threadIdx.x;
  const int lane = tid & 63;
  const int wave = tid >> 6;
  const int wm = wave >> 2;
  const int wn = wave & 3;
  const int wr = wm * 128;
  const int wc = wn * 64;
  const int frow = lane & 15;
  const int kg = lane >> 4;
  const int swz0 = (kg * 16) ^ ((lane & 7) << 4);
  const int swz1 = (64 + kg * 16) ^ ((lane & 7) << 4);

  int bid = blockIdx.x;              // 1024 blocks = 64 groups x 16
  int gid = bid >> 4, lid = bid & 15;
  gid = ((gid & 7) << 3) | (gid >> 3);          // bijective, 64 % 8 == 0
  const int bm = (gid >> 2) * 4 + (lid >> 2);
  const int bn = (gid & 3) * 4 + (lid & 3);
  const int brow = bm * 256, bcol = bn * 256;

  const unsigned short* Abase = A + (size_t)brow * K_DIM;
  const unsigned short* Bbase = BT + (size_t)bcol * K_DIM;

  const int srow = tid >> 3;
  const int scol = ((((tid & 7) << 4) ^ ((srow & 7) << 4)) >> 1);
  const int ldsu = __builtin_amdgcn_readfirstlane(wave * 512);   // shorts

#define STG(dst, base, q, k0) __builtin_amdgcn_global_load_lds( \
    (const __attribute__((address_space(1))) void*)((base) + (size_t)((q)*64 + srow) * K_DIM + (k0) + scol), \
    (__attribute__((address_space(3))) void*)((dst) + (q)*4096 + ldsu), 16, 0, 0)

#define STG4(dst, base, k0) do { STG(dst, base, 0, k0); STG(dst, base, 1, k0); \
                                 STG(dst, base, 2, k0); STG(dst, base, 3, k0); } while (0)

#define LOAD_AH(P, h) { _Pragma("unroll") for (int mi = 0; mi < 4; ++mi) { \
    const char* p_ = (const char*)(P) + (wr + frow + ((h)*4 + mi) * 16) * 128; \
    aF[mi][0] = *(const bf16x8*)(p_ + swz0); aF[mi][1] = *(const bf16x8*)(p_ + swz1); } }

#define LOAD_BH(P, h, dst) { _Pragma("unroll") for (int ni = 0; ni < 2; ++ni) { \
    const char* p_ = (const char*)(P) + (wc + frow + ((h)*2 + ni) * 16) * 128; \
    dst[ni][0] = *(const bf16x8*)(p_ + swz0); dst[ni][1] = *(const bf16x8*)(p_ + swz1); } }

  f32x4 acc[8][4] = {};
  bf16x8 aF[4][2], b0[2][2], b1[2][2];

  // prologue: B0 -> Bl[0], A0 -> Al[0], B1 -> Bl[1]; drain B0+A0, leave B1.
  STG4(Bl[0], Bbase, 0);
  STG4(Al[0], Abase, 0);
  STG4(Bl[1], Bbase, 64);
  WAITV(4);
  PH_BARRIER;

  unsigned short* a_rd = &Al[0][0]; unsigned short* a_st = &Al[1][0];
  unsigned short* b_rd = &Bl[0][0]; unsigned short* b_nx = &Bl[1][0];
  unsigned short* b_st = &Bl[2][0];

#pragma unroll 1
  for (int t = 0; t < 16; ++t) {
    const int k = t * 64;
    LOAD_AH(a_rd, 0); SCHED0;
    LOAD_BH(b_rd, 0, b0); SCHED0;
    LOAD_BH(b_rd, 1, b1); SCHED0;
    if (t < 15) STG4(a_st, Abase, k + 64);        // A_{t+1}
    if (t < 14) STG4(b_st, Bbase, k + 128);       // B_{t+2}
    WAITL(4);                                     // aF-h0 + b0 landed
    quad_mfma(acc, aF, b0, 0, 0);
    WAITL(0);                                     // b1 landed
    quad_mfma(acc, aF, b1, 0, 2);
    LOAD_AH(a_rd, 1); SCHED0;
    WAITL(0);                                     // aF-h1 landed
    quad_mfma(acc, aF, b1, 4, 2);
    quad_mfma(acc, aF, b0, 4, 0);                 // pure-reg quadrant
    if (t < 14) { WAITV(4); } else { WAITV(0); }  // publish: A_{t+1},B_{t+1} in LDS
    PH_BARRIER;
    // rotate buffers
    unsigned short* ta = a_rd; a_rd = a_st; a_st = ta;
    unsigned short* tb = b_rd; b_rd = b_nx; b_nx = b_st; b_st = tb;
  }

  // ---- epilogue: per-wave LDS transpose -> contiguous float4 stores ----
  __syncthreads();
  float* T = (float*)&Al[0][0];                   // 64 KB available, need 34816 B
  float* Tw = T + wave * (16 * 68);
  const int col4 = lane & 15;
  const int rsel = lane >> 4;
  float4 bv = *(const float4*)&bias[bcol + wc + col4 * 4];

#pragma unroll
  for (int mi = 0; mi < 8; ++mi) {
#pragma unroll
    for (int ni = 0; ni < 4; ++ni)
#pragma unroll
      for (int r = 0; r < 4; ++r)
        Tw[(kg * 4 + r) * 68 + ni * 16 + frow] = acc[mi][ni][r];
    WAITL(0);                                     // fence write->read
#pragma unroll
    for (int rr = 0; rr < 4; ++rr) {
      float4 v = *(float4*)&Tw[(rr * 4 + rsel) * 68 + col4 * 4];
      v.x += bv.x; v.y += bv.y; v.z += bv.z; v.w += bv.w;
      *(float4*)&C[(size_t)(brow + wr + mi * 16 + rr * 4 + rsel) * N_DIM + bcol + wc + col4 * 4] = v;
    }
    WAITL(0);                                     // reads done before next overwrite
  }
}

extern "C" void kernel_launch(void* const* d_in, const int* in_sizes, int n_in,
                              void* d_out, int out_size, void* d_ws, size_t ws_size,
                              hipStream_t stream) {
  const float* x    = (const float*)d_in[0];
  const float* a    = (const float*)d_in[1];
  const float* b    = (const float*)d_in[2];
  const float* s    = (const float*)d_in[3];
  const float* bias = (const float*)d_in[4];
  float* out = (float*)d_out;

  unsigned short* xb = (unsigned short*)d_ws;
  unsigned short* wT = (unsigned short*)((char*)d_ws + (size_t)M_DIM * K_DIM * 2);

  prep_kernel<<<CVT_BLOCKS + WT_BLOCKS, 256, 0, stream>>>(x, a, b, s, xb, wT);
  gemm8_kernel<<<(M_DIM / 256) * (N_DIM / 256), 512, 0, stream>>>(xb, wT, bias, out);
}

// Round 9
// 188.102 us; speedup vs baseline: 1.0405x; 1.0405x over previous
//
#include <hip/hip_runtime.h>
#include <hip/hip_bf16.h>

typedef short bf16x8 __attribute__((ext_vector_type(8)));
typedef float f32x4 __attribute__((ext_vector_type(4)));

static constexpr int M_DIM = 16384;
static constexpr int N_DIM = 4096;
static constexpr int K_DIM = 1024;

static constexpr int CVT_BLOCKS = (M_DIM * K_DIM / 8) / 256;   // 8192
static constexpr int WT_BLOCKS  = N_DIM;                       // 4096 (R7 proven)

__device__ __forceinline__ unsigned short f2bf(float f) {
  union { float f; unsigned u; } v; v.f = f;
  unsigned r = v.u + 0x7FFFu + ((v.u >> 16) & 1u);
  return (unsigned short)(r >> 16);
}

// R7-proven fused prep: cvt blocks vectorized; one block per w^T column.
__global__ __launch_bounds__(256) void prep_kernel(
    const float* __restrict__ x, const float* __restrict__ a,
    const float* __restrict__ b, const float* __restrict__ s,
    unsigned short* __restrict__ xb, unsigned short* __restrict__ wT) {
  __shared__ float as_eff[8][64];
  __shared__ float bl[8][16];
  const int tid = threadIdx.x;

  if (blockIdx.x < CVT_BLOCKS) {
    const int i = (blockIdx.x * 256 + tid) * 2;
    float4 v0 = reinterpret_cast<const float4*>(x)[i];
    float4 v1 = reinterpret_cast<const float4*>(x)[i + 1];
    ushort4 o0, o1;
    o0.x = f2bf(v0.x); o0.y = f2bf(v0.y); o0.z = f2bf(v0.z); o0.w = f2bf(v0.w);
    o1.x = f2bf(v1.x); o1.y = f2bf(v1.y); o1.z = f2bf(v1.z); o1.w = f2bf(v1.w);
    reinterpret_cast<ushort4*>(xb)[i] = o0;
    reinterpret_cast<ushort4*>(xb)[i + 1] = o1;
    return;
  }

  const int n = blockIdx.x - CVT_BLOCKS;
  const int j = n >> 5, l = n & 31;

#pragma unroll
  for (int t = tid; t < 512; t += 256) {
    const int r = t >> 6, i = t & 63;
    as_eff[r][i] = a[(r * 64 + i) * 128 + j] * s[i * 128 + j];
  }
  if (tid < 128) {
    const int r = tid >> 4, kk = tid & 15;
    bl[r][kk] = b[(r * 16 + kk) * 32 + l];
  }
  __syncthreads();

  const int i = tid >> 2;
  const int kk0 = (tid & 3) * 4;
  float o[4] = {0.f, 0.f, 0.f, 0.f};
#pragma unroll
  for (int r = 0; r < 8; ++r) {
    const float av = as_eff[r][i];
#pragma unroll
    for (int q = 0; q < 4; ++q)
      o[q] += av * bl[r][kk0 + q];
  }
  ushort4 w4;
  w4.x = f2bf(o[0]); w4.y = f2bf(o[1]); w4.z = f2bf(o[2]); w4.w = f2bf(o[3]);
  *reinterpret_cast<ushort4*>(&wT[(size_t)n * K_DIM + tid * 4]) = w4;
}

// ---- 256x256 GEMM, faithful m201 8-phase discipline (4 phases per K-tile) ----
// C(M,N) = A(M,K) * BT(N,K)^T + bias ; A,BT bf16, C f32.
// 512 threads = 8 waves (2M x 4N); wave out 128x64 = 8x4 frags of 16x16x32.
// LDS: Al[2] + Bl[2] = 128 KiB double-buffer.
// Per phase: {ds_read cluster ; 2-load stage ; [lgkm(8) if 12 reads] ; BAR ;
//             lgkm(0) ; setprio(1) 16 MFMA setprio(0) ; BAR}.
// Ledger (proven R5-R8): tile t reads buf t&1. Stage A(t+1)->other buf at
// P1/P2; stage B(t+2)->current B buf at P3/P4 (all B reads of cur drained at
// P2's lgkm(0), ordered by P2's closing BAR). Publish at P4: queue =
// [B(t+1):4][A(t+1):4][B(t+2):4] -> vmcnt(4) drains exactly what t+1 reads,
// leaves B(t+2) in flight. Tail: t=14 vmcnt(0), t=15 stages nothing.

#define PH_BARRIER __builtin_amdgcn_s_barrier()
#define SCHED0     __builtin_amdgcn_sched_barrier(0)
#define WAITV(N)   do { asm volatile("s_waitcnt vmcnt(" #N ")" ::: "memory"); SCHED0; } while (0)
#define WAITL(N)   do { asm volatile("s_waitcnt lgkmcnt(" #N ")" ::: "memory"); SCHED0; } while (0)

__device__ __forceinline__ void quad_mfma(f32x4 (&acc)[8][4], const bf16x8 (&aH)[4][2],
                                          const bf16x8 (&bH)[2][2], int mbase, int nbase) {
  __builtin_amdgcn_s_setprio(1);
#pragma unroll
  for (int ks = 0; ks < 2; ++ks)
#pragma unroll
    for (int mi = 0; mi < 4; ++mi)
#pragma unroll
      for (int ni = 0; ni < 2; ++ni)
        acc[mbase + mi][nbase + ni] = __builtin_amdgcn_mfma_f32_16x16x32_bf16(
            aH[mi][ks], bH[ni][ks], acc[mbase + mi][nbase + ni], 0, 0, 0);
  __builtin_amdgcn_s_setprio(0);
}

__global__ __launch_bounds__(512, 2) void gemm8_kernel(
    const unsigned short* __restrict__ A, const unsigned short* __restrict__ BT,
    const float* __restrict__ bias, float* __restrict__ C) {
  __shared__ __align__(16) unsigned short Al[2][16384];
  __shared__ __align__(16) unsigned short Bl[2][16384];

  const int tid  = threadIdx.x;
  const int lane = tid & 63;
  const int wave = tid >> 6;
  const int wm = wave >> 2;
  const int wn = wave & 3;
  const int wr = wm * 128;
  const int wc = wn * 64;
  const int frow = lane & 15;
  const int kg = lane >> 4;
  const int swz0 = (kg * 16) ^ ((lane & 7) << 4);
  const int swz1 = (64 + kg * 16) ^ ((lane & 7) << 4);

  int bid = blockIdx.x;              // 1024 blocks = 64 groups x 16
  int gid = bid >> 4, lid = bid & 15;
  gid = ((gid & 7) << 3) | (gid >> 3);          // bijective, 64 % 8 == 0
  const int bm = (gid >> 2) * 4 + (lid >> 2);
  const int bn = (gid & 3) * 4 + (lid & 3);
  const int brow = bm * 256, bcol = bn * 256;

  const unsigned short* Abase = A + (size_t)brow * K_DIM;
  const unsigned short* Bbase = BT + (size_t)bcol * K_DIM;

  const int srow = tid >> 3;
  const int scol = ((((tid & 7) << 4) ^ ((srow & 7) << 4)) >> 1);
  const int ldsu = __builtin_amdgcn_readfirstlane(wave * 512);   // shorts

#define STG(dst, base, q, k0) __builtin_amdgcn_global_load_lds( \
    (const __attribute__((address_space(1))) void*)((base) + (size_t)((q)*64 + srow) * K_DIM + (k0) + scol), \
    (__attribute__((address_space(3))) void*)((dst) + (q)*4096 + ldsu), 16, 0, 0)

#define LOAD_AH(P, h) { _Pragma("unroll") for (int mi = 0; mi < 4; ++mi) { \
    const char* p_ = (const char*)(P) + (wr + frow + ((h)*4 + mi) * 16) * 128; \
    aF[mi][0] = *(const bf16x8*)(p_ + swz0); aF[mi][1] = *(const bf16x8*)(p_ + swz1); } }

#define LOAD_BH(P, h, dst) { _Pragma("unroll") for (int ni = 0; ni < 2; ++ni) { \
    const char* p_ = (const char*)(P) + (wc + frow + ((h)*2 + ni) * 16) * 128; \
    dst[ni][0] = *(const bf16x8*)(p_ + swz0); dst[ni][1] = *(const bf16x8*)(p_ + swz1); } }

  f32x4 acc[8][4] = {};
  bf16x8 aF[4][2], b0[2][2], b1[2][2];

  // prologue: B0+A0 (buf0) + B1 (buf1); vmcnt(4) leaves B1 in flight.
  STG(Bl[0], Bbase, 0, 0);  STG(Bl[0], Bbase, 1, 0);
  STG(Bl[0], Bbase, 2, 0);  STG(Bl[0], Bbase, 3, 0);
  STG(Al[0], Abase, 0, 0);  STG(Al[0], Abase, 1, 0);
  STG(Al[0], Abase, 2, 0);  STG(Al[0], Abase, 3, 0);
  STG(Bl[1], Bbase, 0, 64); STG(Bl[1], Bbase, 1, 64);
  STG(Bl[1], Bbase, 2, 64); STG(Bl[1], Bbase, 3, 64);
  WAITV(4);
  PH_BARRIER;

  unsigned short* a_rd = &Al[0][0]; unsigned short* a_st = &Al[1][0];
  unsigned short* b_rd = &Bl[0][0]; unsigned short* b_st = &Bl[1][0];

#pragma unroll 1
  for (int t = 0; t < 16; ++t) {
    const int k = t * 64;
    // ---- P1: 12 reads + stage A(t+1) h0 ; lgkm(8) throttle ----
    LOAD_AH(a_rd, 0); SCHED0;
    LOAD_BH(b_rd, 0, b0); SCHED0;
    if (t < 15) { STG(a_st, Abase, 0, k + 64); STG(a_st, Abase, 1, k + 64); }
    WAITL(8);
    PH_BARRIER;
    WAITL(0);
    quad_mfma(acc, aF, b0, 0, 0);
    PH_BARRIER;
    // ---- P2: 4 reads + stage A(t+1) h1 ----
    LOAD_BH(b_rd, 1, b1); SCHED0;
    if (t < 15) { STG(a_st, Abase, 2, k + 64); STG(a_st, Abase, 3, k + 64); }
    PH_BARRIER;
    WAITL(0);
    quad_mfma(acc, aF, b1, 0, 2);
    PH_BARRIER;
    // ---- P3: 8 reads + stage B(t+2) h0 (cur B buf; reads drained @P2) ----
    LOAD_AH(a_rd, 1); SCHED0;
    if (t < 14) { STG(b_rd, Bbase, 0, k + 128); STG(b_rd, Bbase, 1, k + 128); }
    PH_BARRIER;
    WAITL(0);
    quad_mfma(acc, aF, b1, 4, 2);
    PH_BARRIER;
    // ---- P4: stage B(t+2) h1 ; reg-only MFMA ; counted publish ----
    if (t < 14) { STG(b_rd, Bbase, 2, k + 128); STG(b_rd, Bbase, 3, k + 128); }
    PH_BARRIER;
    quad_mfma(acc, aF, b0, 4, 0);
    if (t < 14) { WAITV(4); } else if (t == 14) { WAITV(0); }
    PH_BARRIER;
    // swap buffers
    unsigned short* tp = a_rd; a_rd = a_st; a_st = tp;
    tp = b_rd; b_rd = b_st; b_st = tp;
  }

  // ---- epilogue: per-wave LDS transpose -> contiguous float4 stores ----
  __syncthreads();
  float* T = (float*)&Al[0][0];
  float* Tw = T + wave * (16 * 68);
  const int col4 = lane & 15;
  const int rsel = lane >> 4;
  float4 bv = *(const float4*)&bias[bcol + wc + col4 * 4];

#pragma unroll
  for (int mi = 0; mi < 8; ++mi) {
#pragma unroll
    for (int ni = 0; ni < 4; ++ni)
#pragma unroll
      for (int r = 0; r < 4; ++r)
        Tw[(kg * 4 + r) * 68 + ni * 16 + frow] = acc[mi][ni][r];
    WAITL(0);                                   // fence write->read (R2/R3 root cause)
#pragma unroll
    for (int rr = 0; rr < 4; ++rr) {
      float4 v = *(float4*)&Tw[(rr * 4 + rsel) * 68 + col4 * 4];
      v.x += bv.x; v.y += bv.y; v.z += bv.z; v.w += bv.w;
      *(float4*)&C[(size_t)(brow + wr + mi * 16 + rr * 4 + rsel) * N_DIM + bcol + wc + col4 * 4] = v;
    }
    WAITL(0);                                   // reads done before next overwrite
  }
}

extern "C" void kernel_launch(void* const* d_in, const int* in_sizes, int n_in,
                              void* d_out, int out_size, void* d_ws, size_t ws_size,
                              hipStream_t stream) {
  const float* x    = (const float*)d_in[0];
  const float* a    = (const float*)d_in[1];
  const float* b    = (const float*)d_in[2];
  const float* s    = (const float*)d_in[3];
  const float* bias = (const float*)d_in[4];
  float* out = (float*)d_out;

  unsigned short* xb = (unsigned short*)d_ws;
  unsigned short* wT = (unsigned short*)((char*)d_ws + (size_t)M_DIM * K_DIM * 2);

  prep_kernel<<<CVT_BLOCKS + WT_BLOCKS, 256, 0, stream>>>(x, a, b, s, xb, wT);
  gemm8_kernel<<<(M_DIM / 256) * (N_DIM / 256), 512, 0, stream>>>(xb, wT, bias, out);
}